// Round 1
// baseline (174.725 us; speedup 1.0000x reference)
//
#include <hip/hip_runtime.h>
#include <math.h>

#define N_SAMPLES 4096
#define S_DIM 512
#define A_DIM 16
#define ACT_DIM 20
#define E_DIM 64
#define M_DIM 320      // A*ACT
#define J_DIM 1216     // 1024 (W_h1) + 64 (W_b1) + 64 (W_hf) + 64 (W_v1)

#define BM 128
#define BN 128
#define BK 32

// K1: C[n, j] = state[n,:] . Wcat[j,:]  (+ bias at store), routed to 4 ws buffers.
__global__ __launch_bounds__(256) void hyper_gemm(
    const float* __restrict__ S,
    const float* __restrict__ Wh1, const float* __restrict__ bh1,
    const float* __restrict__ Wb1, const float* __restrict__ bb1,
    const float* __restrict__ Whf, const float* __restrict__ bhf,
    const float* __restrict__ Wv1, const float* __restrict__ bv1,
    float* __restrict__ w1_all, float* __restrict__ b1_all,
    float* __restrict__ wf_all, float* __restrict__ hv_all)
{
    __shared__ alignas(16) float As[BK][BM + 4];  // k-major, pad keeps 16B align + banks spread
    __shared__ alignas(16) float Bs[BK][BN + 4];

    const int tid = threadIdx.x;
    const int n0 = blockIdx.x * BM;
    const int j0 = blockIdx.y * BN;
    const int ty = tid >> 4;   // 0..15
    const int tx = tid & 15;   // 0..15

    float acc[8][8];
#pragma unroll
    for (int i = 0; i < 8; ++i)
#pragma unroll
        for (int j = 0; j < 8; ++j) acc[i][j] = 0.f;

    for (int k0 = 0; k0 < S_DIM; k0 += BK) {
        // A tile: 128 rows x 32 k  -> 1024 float4, 4 per thread, coalesced
#pragma unroll
        for (int it = 0; it < 4; ++it) {
            int p   = tid + it * 256;
            int row = p >> 3;
            int kc  = (p & 7) << 2;
            float4 v = *reinterpret_cast<const float4*>(
                S + (size_t)(n0 + row) * S_DIM + k0 + kc);
            As[kc + 0][row] = v.x;
            As[kc + 1][row] = v.y;
            As[kc + 2][row] = v.z;
            As[kc + 3][row] = v.w;
        }
        // B tile: 128 cols x 32 k, row pointer routed per j-range
#pragma unroll
        for (int it = 0; it < 4; ++it) {
            int p   = tid + it * 256;
            int col = p >> 3;
            int kc  = (p & 7) << 2;
            int j   = j0 + col;
            float4 v = make_float4(0.f, 0.f, 0.f, 0.f);
            if (j < J_DIM) {
                const float* wrow;
                if (j < 1024)      wrow = Wh1 + (size_t)j * S_DIM;
                else if (j < 1088) wrow = Wb1 + (size_t)(j - 1024) * S_DIM;
                else if (j < 1152) wrow = Whf + (size_t)(j - 1088) * S_DIM;
                else               wrow = Wv1 + (size_t)(j - 1152) * S_DIM;
                v = *reinterpret_cast<const float4*>(wrow + k0 + kc);
            }
            Bs[kc + 0][col] = v.x;
            Bs[kc + 1][col] = v.y;
            Bs[kc + 2][col] = v.z;
            Bs[kc + 3][col] = v.w;
        }
        __syncthreads();

#pragma unroll 8
        for (int kk = 0; kk < BK; ++kk) {
            float a[8], b[8];
            *reinterpret_cast<float4*>(&a[0]) = *reinterpret_cast<const float4*>(&As[kk][ty * 8]);
            *reinterpret_cast<float4*>(&a[4]) = *reinterpret_cast<const float4*>(&As[kk][ty * 8 + 4]);
            *reinterpret_cast<float4*>(&b[0]) = *reinterpret_cast<const float4*>(&Bs[kk][tx * 8]);
            *reinterpret_cast<float4*>(&b[4]) = *reinterpret_cast<const float4*>(&Bs[kk][tx * 8 + 4]);
#pragma unroll
            for (int i = 0; i < 8; ++i)
#pragma unroll
                for (int j = 0; j < 8; ++j)
                    acc[i][j] = fmaf(a[i], b[j], acc[i][j]);
        }
        __syncthreads();
    }

    // store with bias, routed
#pragma unroll
    for (int i = 0; i < 8; ++i) {
        int n = n0 + ty * 8 + i;
#pragma unroll
        for (int jj = 0; jj < 8; ++jj) {
            int j = j0 + tx * 8 + jj;
            if (j >= J_DIM) continue;
            float val = acc[i][jj];
            if (j < 1024)      w1_all[(size_t)n * 1024 + j]          = val + bh1[j];
            else if (j < 1088) b1_all[(size_t)n * 64 + (j - 1024)]   = val + bb1[j - 1024];
            else if (j < 1152) wf_all[(size_t)n * 64 + (j - 1088)]   = val + bhf[j - 1088];
            else               hv_all[(size_t)n * 64 + (j - 1152)]   = val + bv1[j - 1152];
        }
    }
}

// K2: per-sample mixer using the rank-1 counterfactual identity.
__global__ __launch_bounds__(320) void mixer(
    const float* __restrict__ q_agents, const int* __restrict__ actions,
    const float* __restrict__ w1_all, const float* __restrict__ b1_all,
    const float* __restrict__ wf_all, const float* __restrict__ hv_all,
    const float* __restrict__ Wv2, const float* __restrict__ bv2,
    float* __restrict__ out)
{
    const int n = blockIdx.x;
    const int tid = threadIdx.x;

    __shared__ float w1s[A_DIM][E_DIM + 1];
    __shared__ float b1s[E_DIM];
    __shared__ float wfs[E_DIM];
    __shared__ float bases[E_DIM];
    __shared__ float qts[A_DIM];
    __shared__ float v_sh;

    for (int idx = tid; idx < A_DIM * E_DIM; idx += 320)
        w1s[idx >> 6][idx & 63] = w1_all[(size_t)n * 1024 + idx];
    if (tid < E_DIM) {
        b1s[tid] = b1_all[(size_t)n * 64 + tid];
        wfs[tid] = wf_all[(size_t)n * 64 + tid];
    }
    if (tid < A_DIM) {
        int a = actions[n * A_DIM + tid];
        qts[tid] = q_agents[((size_t)n * A_DIM + tid) * ACT_DIM + a];
    }
    __syncthreads();

    // wave 1 computes v = relu(hv).Wv2 + bv2
    if (tid >= 64 && tid < 128) {
        int e = tid - 64;
        float p = fmaxf(hv_all[(size_t)n * 64 + e], 0.f) * Wv2[e];
#pragma unroll
        for (int off = 32; off > 0; off >>= 1) p += __shfl_down(p, off, 64);
        if (e == 0) v_sh = p + bv2[0];
    }
    // wave 0 computes base[e] = sum_a qt[a] * w1[a,e]
    if (tid < 64) {
        float s = 0.f;
#pragma unroll
        for (int a = 0; a < A_DIM; ++a) s += qts[a] * w1s[a][tid];
        bases[tid] = s;
    }
    __syncthreads();

    // one thread per counterfactual row m = (i, act)
    {
        int m = tid;                 // blockDim == M_DIM == 320
        int i = m / ACT_DIM;
        int act = m - i * ACT_DIM;
        float delta = q_agents[((size_t)n * A_DIM + i) * ACT_DIM + act] - qts[i];
        float accv = 0.f;
#pragma unroll 8
        for (int e = 0; e < E_DIM; ++e) {
            float pre = bases[e] + delta * w1s[i][e] + b1s[e];
            float h = pre > 0.f ? pre : expm1f(pre);
            accv = fmaf(h, wfs[e], accv);
        }
        out[(size_t)n * M_DIM + m] = accv + v_sh;
    }
}

extern "C" void kernel_launch(void* const* d_in, const int* in_sizes, int n_in,
                              void* d_out, int out_size, void* d_ws, size_t ws_size,
                              hipStream_t stream)
{
    const float* q_agents = (const float*)d_in[0];
    const int*   actions  = (const int*)d_in[1];
    const float* state    = (const float*)d_in[2];
    const float* Wh1 = (const float*)d_in[3];
    const float* bh1 = (const float*)d_in[4];
    const float* Wb1 = (const float*)d_in[5];
    const float* bb1 = (const float*)d_in[6];
    const float* Whf = (const float*)d_in[7];
    const float* bhf = (const float*)d_in[8];
    const float* Wv1 = (const float*)d_in[9];
    const float* bv1 = (const float*)d_in[10];
    const float* Wv2 = (const float*)d_in[11];
    const float* bv2 = (const float*)d_in[12];
    float* out = (float*)d_out;

    float* w1_all = (float*)d_ws;                               // 4096*1024
    float* b1_all = w1_all + (size_t)N_SAMPLES * 1024;          // 4096*64
    float* wf_all = b1_all + (size_t)N_SAMPLES * 64;            // 4096*64
    float* hv_all = wf_all + (size_t)N_SAMPLES * 64;            // 4096*64

    dim3 g1(N_SAMPLES / BM, (J_DIM + BN - 1) / BN);
    hipLaunchKernelGGL(hyper_gemm, g1, dim3(256), 0, stream,
                       state, Wh1, bh1, Wb1, bb1, Whf, bhf, Wv1, bv1,
                       w1_all, b1_all, wf_all, hv_all);
    hipLaunchKernelGGL(mixer, dim3(N_SAMPLES), dim3(320), 0, stream,
                       q_agents, actions, w1_all, b1_all, wf_all, hv_all,
                       Wv2, bv2, out);
}

// Round 2
// 56.717 us; speedup vs baseline: 3.0806x; 3.0806x over previous
//
#include <hip/hip_runtime.h>
#include <math.h>
#include <stdint.h>

#define N_SAMPLES 4096
#define S_DIM 512
#define A_DIM 16
#define ACT_DIM 20
#define E_DIM 64
#define M_DIM 320      // A*ACT
#define J_DIM 1216     // 1024 (W_h1) + 64 (W_b1) + 64 (W_hf) + 64 (W_v1)
#define JPAD 1280      // padded to 10 * 128 so staging never goes OOB

using bf16x8  = __attribute__((ext_vector_type(8))) short;
using f32x4   = __attribute__((ext_vector_type(4))) float;
using ushort8 = __attribute__((ext_vector_type(8))) unsigned short;

__device__ __forceinline__ unsigned short f2bf(float x) {  // RNE f32 -> bf16
    uint32_t u = __float_as_uint(x);
    u += 0x7fffu + ((u >> 16) & 1u);
    return (unsigned short)(u >> 16);
}
__device__ __forceinline__ float bf2f(unsigned short u) {
    return __uint_as_float(((uint32_t)u) << 16);
}

// ---------------------------------------------------------------- K0: convert
// Abf[4096][512] <- state ; Bbf[1280][512] <- {Wh1,Wb1,Whf,Wv1, zeros}
__global__ __launch_bounds__(256) void cvt_bf16(
    const float* __restrict__ S,
    const float* __restrict__ Wh1, const float* __restrict__ Wb1,
    const float* __restrict__ Whf, const float* __restrict__ Wv1,
    unsigned short* __restrict__ Abf, unsigned short* __restrict__ Bbf)
{
    const int A_QUADS = N_SAMPLES * S_DIM / 4;   // 524288
    const int B_QUADS = JPAD * S_DIM / 4;        // 163840
    int idx = blockIdx.x * 256 + threadIdx.x;
    if (idx < A_QUADS) {
        float4 v = reinterpret_cast<const float4*>(S)[idx];
        ushort4 o = { f2bf(v.x), f2bf(v.y), f2bf(v.z), f2bf(v.w) };
        reinterpret_cast<ushort4*>(Abf)[idx] = o;
    } else if (idx < A_QUADS + B_QUADS) {
        int q   = idx - A_QUADS;
        int row = q >> 7;          // 128 quads per 512-elem row
        int qc  = q & 127;
        ushort4 o = {0, 0, 0, 0};
        const float* src = nullptr;
        if (row < 1024)      src = Wh1 + (size_t)row * S_DIM;
        else if (row < 1088) src = Wb1 + (size_t)(row - 1024) * S_DIM;
        else if (row < 1152) src = Whf + (size_t)(row - 1088) * S_DIM;
        else if (row < 1216) src = Wv1 + (size_t)(row - 1152) * S_DIM;
        if (src) {
            float4 v = reinterpret_cast<const float4*>(src)[qc];
            o = ushort4{ f2bf(v.x), f2bf(v.y), f2bf(v.z), f2bf(v.w) };
        }
        reinterpret_cast<ushort4*>(Bbf)[q] = o;
    }
}

// ---------------------------------------------------------------- K1: MFMA GEMM
// C[n,j] = sum_k Abf[n,k]*Bbf[j,k]  (+bias at store), 128x128 tile, BK=32.
#define GL2L16(g, l) __builtin_amdgcn_global_load_lds(                        \
    (const __attribute__((address_space(1))) void*)(g),                      \
    (__attribute__((address_space(3))) void*)(l), 16, 0, 0)

__global__ __launch_bounds__(256, 2) void gemm_bf16(
    const unsigned short* __restrict__ Abf,
    const unsigned short* __restrict__ Bbf,
    const float* __restrict__ bh1, const float* __restrict__ bb1,
    const float* __restrict__ bhf, const float* __restrict__ bv1,
    unsigned short* __restrict__ w1_bf,
    float* __restrict__ b1_all, float* __restrict__ wf_all,
    float* __restrict__ hv_all)
{
    __shared__ short As[128 * 32];   // row-major [row][32], 64 B/row
    __shared__ short Bs[128 * 32];

    const int tid  = threadIdx.x;
    const int lane = tid & 63;
    const int wave = tid >> 6;
    const int n0 = blockIdx.x * 128;
    const int j0 = blockIdx.y * 128;

    // staging: 4x global_load_lds (16B/lane) per wave per k-step.
    // XOR chunk swizzle applied on the GLOBAL source (both-sides rule):
    // LDS[row][c] holds global chunk c ^ ((row>>1)&3).
    const int gchunk = (lane & 3) ^ ((lane >> 3) & 3);
    const int srow   = wave * 32 + (lane >> 2);
    const unsigned short* gA0 = Abf + (size_t)(n0 + srow) * S_DIM + gchunk * 8;
    const unsigned short* gA1 = gA0 + 16 * S_DIM;
    const unsigned short* gB0 = Bbf + (size_t)(j0 + srow) * S_DIM + gchunk * 8;
    const unsigned short* gB1 = gB0 + 16 * S_DIM;
    short* lA0 = &As[(wave * 32) * 32];
    short* lA1 = &As[(wave * 32 + 16) * 32];
    short* lB0 = &Bs[(wave * 32) * 32];
    short* lB1 = &Bs[(wave * 32 + 16) * 32];

    // fragment reads: wave (wr,wc) owns 64x64; 4x4 16x16 frags.
    const int wr = wave >> 1, wc = wave & 1;
    const int l16 = lane & 15, lk = lane >> 4;
    const int rchunk = lk ^ ((l16 >> 1) & 3);   // undo the write-side swizzle
    const short* pA = &As[(wr * 64 + l16) * 32 + rchunk * 8];
    const short* pB = &Bs[(wc * 64 + l16) * 32 + rchunk * 8];

    f32x4 acc[4][4] = {};

#pragma unroll 1
    for (int ks = 0; ks < S_DIM / 32; ++ks) {
        GL2L16(gA0, lA0);
        GL2L16(gA1, lA1);
        GL2L16(gB0, lB0);
        GL2L16(gB1, lB1);
        gA0 += 32; gA1 += 32; gB0 += 32; gB1 += 32;
        __syncthreads();
        bf16x8 a[4], b[4];
#pragma unroll
        for (int m = 0; m < 4; ++m)
            a[m] = *reinterpret_cast<const bf16x8*>(pA + m * 512);
#pragma unroll
        for (int n = 0; n < 4; ++n)
            b[n] = *reinterpret_cast<const bf16x8*>(pB + n * 512);
#pragma unroll
        for (int m = 0; m < 4; ++m)
#pragma unroll
            for (int n = 0; n < 4; ++n)
                acc[m][n] = __builtin_amdgcn_mfma_f32_16x16x32_bf16(
                    a[m], b[n], acc[m][n], 0, 0, 0);
        __syncthreads();
    }

    // epilogue: C/D layout col=lane&15, row=(lane>>4)*4+reg (m89-verified)
    const int orow = n0 + wr * 64 + lk * 4;
    const int ocol = j0 + wc * 64 + l16;
#pragma unroll
    for (int m = 0; m < 4; ++m) {
#pragma unroll
        for (int n = 0; n < 4; ++n) {
            int j = ocol + n * 16;
#pragma unroll
            for (int r = 0; r < 4; ++r) {
                int row = orow + m * 16 + r;
                float val = acc[m][n][r];
                if (j < 1024)
                    w1_bf[(size_t)row * 1024 + j] = f2bf(val + bh1[j]);
                else if (j < 1088)
                    b1_all[(size_t)row * 64 + (j - 1024)] = val + bb1[j - 1024];
                else if (j < 1152)
                    wf_all[(size_t)row * 64 + (j - 1088)] = val + bhf[j - 1088];
                else if (j < J_DIM)
                    hv_all[(size_t)row * 64 + (j - 1152)] = val + bv1[j - 1152];
            }
        }
    }
}

// ---------------------------------------------------------------- K2: mixer
__global__ __launch_bounds__(320) void mixer(
    const float* __restrict__ q_agents, const int* __restrict__ actions,
    const unsigned short* __restrict__ w1_bf, const float* __restrict__ b1_all,
    const float* __restrict__ wf_all, const float* __restrict__ hv_all,
    const float* __restrict__ Wv2, const float* __restrict__ bv2,
    float* __restrict__ out)
{
    const int n = blockIdx.x;
    const int tid = threadIdx.x;

    __shared__ float w1s[A_DIM][E_DIM + 1];
    __shared__ float b1s[E_DIM];
    __shared__ float wfs[E_DIM];
    __shared__ float bases[E_DIM];
    __shared__ float qts[A_DIM];
    __shared__ float v_sh;

    if (tid < 128) {
        ushort8 v = *reinterpret_cast<const ushort8*>(
            w1_bf + (size_t)n * 1024 + tid * 8);
        int a = tid >> 3, e0 = (tid & 7) * 8;
#pragma unroll
        for (int q = 0; q < 8; ++q) w1s[a][e0 + q] = bf2f((unsigned short)v[q]);
    }
    if (tid >= 192 && tid < 256) {
        int e = tid - 192;
        b1s[e] = b1_all[(size_t)n * 64 + e];
        wfs[e] = wf_all[(size_t)n * 64 + e];
    }
    if (tid >= 256 && tid < 256 + A_DIM) {
        int a = tid - 256;
        int act = actions[n * A_DIM + a];
        qts[a] = q_agents[((size_t)n * A_DIM + a) * ACT_DIM + act];
    }
    __syncthreads();

    // wave 2: v = relu(hv).Wv2 + bv2
    if (tid >= 128 && tid < 192) {
        int e = tid - 128;
        float p = fmaxf(hv_all[(size_t)n * 64 + e], 0.f) * Wv2[e];
#pragma unroll
        for (int off = 32; off > 0; off >>= 1) p += __shfl_down(p, off, 64);
        if (e == 0) v_sh = p + bv2[0];
    }
    // wave 0: base[e] = sum_a qt[a] * w1[a,e]
    if (tid < 64) {
        float s = 0.f;
#pragma unroll
        for (int a = 0; a < A_DIM; ++a) s += qts[a] * w1s[a][tid];
        bases[tid] = s;
    }
    __syncthreads();

    // one thread per counterfactual row m = (i, act)
    {
        int m = tid;                 // blockDim == 320 == M_DIM
        int i = m / ACT_DIM;
        int act = m - i * ACT_DIM;
        float delta = q_agents[((size_t)n * A_DIM + i) * ACT_DIM + act] - qts[i];
        float accv = 0.f;
#pragma unroll 8
        for (int e = 0; e < E_DIM; ++e) {
            float pre = bases[e] + delta * w1s[i][e] + b1s[e];
            float h = pre > 0.f ? pre : (__expf(pre) - 1.f);
            accv = fmaf(h, wfs[e], accv);
        }
        out[(size_t)n * M_DIM + m] = accv + v_sh;
    }
}

extern "C" void kernel_launch(void* const* d_in, const int* in_sizes, int n_in,
                              void* d_out, int out_size, void* d_ws, size_t ws_size,
                              hipStream_t stream)
{
    const float* q_agents = (const float*)d_in[0];
    const int*   actions  = (const int*)d_in[1];
    const float* state    = (const float*)d_in[2];
    const float* Wh1 = (const float*)d_in[3];
    const float* bh1 = (const float*)d_in[4];
    const float* Wb1 = (const float*)d_in[5];
    const float* bb1 = (const float*)d_in[6];
    const float* Whf = (const float*)d_in[7];
    const float* bhf = (const float*)d_in[8];
    const float* Wv1 = (const float*)d_in[9];
    const float* bv1 = (const float*)d_in[10];
    const float* Wv2 = (const float*)d_in[11];
    const float* bv2 = (const float*)d_in[12];
    float* out = (float*)d_out;

    // ws layout (bytes):
    char* ws = (char*)d_ws;
    unsigned short* Abf   = (unsigned short*)ws;                        // 4096*512*2   = 4 MB
    unsigned short* Bbf   = (unsigned short*)(ws + 4194304);            // 1280*512*2   = 1.31 MB
    unsigned short* w1_bf = (unsigned short*)(ws + 5505024);            // 4096*1024*2  = 8 MB
    float* b1_all = (float*)(ws + 5505024 + 8388608);                   // 4096*64*4    = 1 MB
    float* wf_all = b1_all + (size_t)N_SAMPLES * 64;
    float* hv_all = wf_all + (size_t)N_SAMPLES * 64;

    const int total_quads = N_SAMPLES * S_DIM / 4 + JPAD * S_DIM / 4;   // 688128
    hipLaunchKernelGGL(cvt_bf16, dim3((total_quads + 255) / 256), dim3(256), 0, stream,
                       state, Wh1, Wb1, Whf, Wv1, Abf, Bbf);

    dim3 g1(N_SAMPLES / 128, JPAD / 128);
    hipLaunchKernelGGL(gemm_bf16, g1, dim3(256), 0, stream,
                       Abf, Bbf, bh1, bb1, bhf, bv1,
                       w1_bf, b1_all, wf_all, hv_all);

    hipLaunchKernelGGL(mixer, dim3(N_SAMPLES), dim3(320), 0, stream,
                       q_agents, actions, w1_bf, b1_all, wf_all, hv_all,
                       Wv2, bv2, out);
}